// Round 19
// baseline (1344.103 us; speedup 1.0000x reference)
//
#include <hip/hip_runtime.h>
#include <hip/hip_bf16.h>

typedef __bf16 bf16x8 __attribute__((ext_vector_type(8)));
typedef float f32x4 __attribute__((ext_vector_type(4)));
typedef float f32x4u __attribute__((ext_vector_type(4), aligned(4)));

#define NH 12
#define HD 64
#define SEQ 145
#define SP 160
#define DMODEL 768
#define NTOT 2304
#define BDIM 1024
#define RBS 148   // rbias padded row stride (4-aligned float4 rows)

// f32 -> bf16 RNE
__device__ __forceinline__ ushort f2bf(float f) {
  union { float f; uint u; } a; a.f = f;
  uint u = a.u;
  return (ushort)((u + 0x7FFFu + ((u >> 16) & 1u)) >> 16);
}

__device__ __forceinline__ uint pk2(float lo, float hi) {
  return (uint)f2bf(lo) | ((uint)f2bf(hi) << 16);
}

__device__ __forceinline__ int relidx(int qi, int ki) {
  if (ki == 0) return (qi == 0) ? 531 : 530;
  if (qi == 0) return 529;
  int q = qi - 1, k = ki - 1;
  int qh = q / 12, qw = q - qh * 12;
  int kh = k / 12, kw = k - kh * 12;
  return (qh - kh + 11) * 23 + (qw - kw + 11);
}

// async global->LDS, 16B per lane; lds dest = wave-uniform base + lane*16
__device__ __forceinline__ void gload_lds16(const ushort* g, ushort* l) {
  __builtin_amdgcn_global_load_lds(
      (const __attribute__((address_space(1))) void*)g,
      (__attribute__((address_space(3))) void*)l, 16, 0, 0);
}

#define VMCNT(n) do { asm volatile("s_waitcnt vmcnt(" #n ")" ::: "memory"); \
                      __builtin_amdgcn_sched_barrier(0); } while (0)
#define LGKM0 do { asm volatile("s_waitcnt lgkmcnt(0)" ::: "memory"); \
                   __builtin_amdgcn_sched_barrier(0); } while (0)

// ---------------- prep: Wt[n][k] = W_sel[k][n%768] as bf16 ----------------
__global__ void prep_w(const float* __restrict__ Wq, const float* __restrict__ Wk,
                       const float* __restrict__ Wv, ushort* __restrict__ Wt) {
  int i = blockIdx.x * 256 + threadIdx.x;
  if (i >= NTOT * DMODEL) return;
  int n = i / DMODEL, k = i - n * DMODEL;
  const float* W = (n < DMODEL) ? Wq : (n < 2 * DMODEL ? Wk : Wv);
  int c = n % DMODEL;
  Wt[i] = f2bf(W[k * DMODEL + c]);
}

// ---------------- zero pad region of transposed V buffer ----------------
__global__ void zero_vpad(ushort* __restrict__ vbuf) {
  int i = blockIdx.x * 256 + threadIdx.x;
  const int total = BDIM * NH * HD * (SP - SEQ);
  if (i >= total) return;
  int s = SEQ + i % (SP - SEQ);
  int row = i / (SP - SEQ);
  vbuf[(size_t)row * SP + s] = 0;
}

// ---------------- rel bias table: rbias[h][qi][ki], row stride RBS ----------------
__global__ void rel_prep(const float* __restrict__ tbl, float* __restrict__ rbias) {
  int i = blockIdx.x * 256 + threadIdx.x;
  if (i >= NH * SEQ * RBS) return;
  int h = i / (SEQ * RBS);
  int rem = i - h * SEQ * RBS;
  int qi = rem / RBS, ki = rem - qi * RBS;
  rbias[i] = (ki < SEQ) ? tbl[relidx(qi, ki) * NH + h] : 0.f;
}

// ---------------- fused QKV GEMM: x f32 [148480,768] x Wt [768,2304] -------
// 128x256 tile, 8 waves (2x4), per-wave 64x64; BK=32 TRIPLE-buffered (72 KB
// LDS -> 2 blocks/CU). A is REG-STAGED from f32 x (fuses the old x2bf pass):
// loads issued 2 tiles ahead, cvt+ds_write 1 tile ahead; B via global_load_lds
// 2 tiles ahead; vmcnt(4) retires exactly tile t+1's 4 loads. V-epilogue
// transposes through per-wave LDS for coalesced 16B stores.
#define GNT 9
#define GNWG 10440   // 1160 * 9
#define NKT 24       // 768 / 32

__global__ __launch_bounds__(512, 4)
void qkv_gemm(const float* __restrict__ x, const ushort* __restrict__ Wt,
              const float* __restrict__ bq, const float* __restrict__ bv,
              ushort* __restrict__ qbuf, ushort* __restrict__ kbuf,
              ushort* __restrict__ vbuf) {
  // A[3][4096] at 0; B[3][8192] at 12288 (ushort indices). 72 KB total.
  // After the K-loop: 8 x 4608-ushort per-wave transpose scratch (V epilogue).
  __shared__ __align__(16) ushort lds[36864];

  int bid = blockIdx.x;
  int logical = (bid & 7) * 1305 + (bid >> 3);   // 10440 % 8 == 0, bijective
  int mt = logical / GNT, nt = logical - (logical / GNT) * GNT;
  int m0 = mt * 128, n0 = nt * 256;

  int tid = threadIdx.x;
  int l = tid & 63, w = tid >> 6;
  int wm = w >> 2, wn = w & 3;          // 2 x 4 wave grid
  int l15 = l & 15, l4 = l >> 4;
  int rslot = l4 ^ ((l15 >> 1) & 3);    // read-side swizzle (BK=32: 4 slots)

  // A reg-staging: thread t -> row (t>>2), data k-chunk (t&3);
  // ds_write phys slot = (t&3) ^ ((row>>1)&3) = (t&3) ^ ((t>>3)&3).
  int arow = tid >> 2;                  // 0..127
  const float* xf = x + (size_t)(m0 + arow) * DMODEL + (tid & 3) * 8;
  int awaddr = (arow << 5) + (((tid & 3) ^ ((tid >> 3) & 3)) << 3);

  // B staging via gload_lds: inverse-swizzled source chunk
  int schunk = (tid & 3) ^ ((tid >> 3) & 3);
  const ushort* bSrc0 = Wt + (size_t)(n0 + arow) * DMODEL + schunk * 8;
  const ushort* bSrc1 = Wt + (size_t)(n0 + 128 + arow) * DMODEL + schunk * 8;
  int wdst = w << 9;   // w*512 ushorts (wave-contiguous dest)

#define ALOAD(s0, s1, kof) do { \
    s0 = *reinterpret_cast<const float4*>(xf + (kof)); \
    s1 = *reinterpret_cast<const float4*>(xf + (kof) + 4); \
  } while (0)
#define ACVTW(db, s0, s1) do { \
    uint4 o_; \
    o_.x = pk2(s0.x, s0.y); o_.y = pk2(s0.z, s0.w); \
    o_.z = pk2(s1.x, s1.y); o_.w = pk2(s1.z, s1.w); \
    *reinterpret_cast<uint4*>(&lds[(db) * 4096 + awaddr]) = o_; \
  } while (0)
#define STAGE_B(db, kof) do { \
    gload_lds16(bSrc0 + (kof), &lds[12288 + (db) * 8192 + wdst]); \
    gload_lds16(bSrc1 + (kof), &lds[12288 + (db) * 8192 + 4096 + wdst]); \
  } while (0)

  f32x4 acc[4][4];
  #pragma unroll
  for (int m = 0; m < 4; m++)
    #pragma unroll
    for (int n = 0; n < 4; n++)
      #pragma unroll
      for (int e = 0; e < 4; e++) acc[m][n][e] = 0.f;

  bf16x8 af[4], bfv[4];

#define LOADFRAG(db) do { \
    int ab_ = (db) * 4096, bb_ = 12288 + (db) * 8192; \
    _Pragma("unroll") \
    for (int i_ = 0; i_ < 4; i_++) \
      af[i_] = *reinterpret_cast<const bf16x8*>( \
          &lds[ab_ + ((wm * 64 + i_ * 16 + l15) << 5) + rslot * 8]); \
    _Pragma("unroll") \
    for (int n_ = 0; n_ < 4; n_++) \
      bfv[n_] = *reinterpret_cast<const bf16x8*>( \
          &lds[bb_ + ((wn * 64 + n_ * 16 + l15) << 5) + rslot * 8]); \
  } while (0)
#define MFMA16() do { \
    __builtin_amdgcn_s_setprio(1); \
    _Pragma("unroll") \
    for (int i_ = 0; i_ < 4; i_++) \
      _Pragma("unroll") \
      for (int n_ = 0; n_ < 4; n_++) \
        acc[i_][n_] = __builtin_amdgcn_mfma_f32_16x16x32_bf16( \
            af[i_], bfv[n_], acc[i_][n_], 0, 0, 0); \
    __builtin_amdgcn_s_setprio(0); \
  } while (0)

  float4 aE0, aE1, aO0, aO1;   // even/odd tile reg-staging sets

  // prologue: issue A0, B0, A1, B1 (8 loads); retire first 4; write A0.
  ALOAD(aE0, aE1, 0);
  STAGE_B(0, 0);
  ALOAD(aO0, aO1, 32);
  STAGE_B(1, 32);
  VMCNT(4);                    // A0 + B0 arrived; A1/B1 in flight
  ACVTW(0, aE0, aE1);
  LGKM0;
  __builtin_amdgcn_s_barrier();

  #pragma unroll
  for (int t = 0; t < NKT; ++t) {
    // issue tile t+2 (A into the set holding tile t, already consumed)
    if (t + 2 < NKT) {
      if ((t & 1) == 0) ALOAD(aE0, aE1, (t + 2) * 32);
      else              ALOAD(aO0, aO1, (t + 2) * 32);
      STAGE_B((t + 2) % 3, (t + 2) * 32);
    }
    // retire tile t+1's loads; cvt+publish its A
    if (t + 1 < NKT) {
      if (t + 2 < NKT) { VMCNT(4); } else { VMCNT(0); }
      if ((t & 1) == 0) ACVTW((t + 1) % 3, aO0, aO1);
      else              ACVTW((t + 1) % 3, aE0, aE1);
    }
    LOADFRAG(t % 3);           // tile t (published at t-1's barrier)
    MFMA16();                  // lgkmcnt waits auto-inserted before use
    if (t < NKT - 1) {
      LGKM0;                   // drain A(t+1) ds_write before publish
      __builtin_amdgcn_s_barrier();
    }
  }

  // ---- epilogue ----
  int which = n0 / DMODEL;
  int h_[4], dh_[4];
  float bias_[4];
  #pragma unroll
  for (int nn = 0; nn < 4; nn++) {
    int col = n0 + wn * 64 + nn * 16 + l15;
    int hcol = col - which * DMODEL;
    h_[nn] = hcol >> 6; dh_[nn] = hcol & 63;
    bias_[nn] = (which == 0) ? bq[hcol] : (which == 2 ? bv[hcol] : 0.f);
  }

  if (which != 2) {
    // q / k: direct stores (dh consecutive per l15)
    #pragma unroll
    for (int i = 0; i < 4; i++) {
      #pragma unroll
      for (int r = 0; r < 4; r++) {
        int row = m0 + wm * 64 + i * 16 + (l4 << 2) + r;
        int b = row / SEQ;
        int s = row - b * SEQ;
        #pragma unroll
        for (int nn = 0; nn < 4; nn++) {
          float v = acc[i][nn][r] + bias_[nn];
          size_t bh = (size_t)b * NH + h_[nn];
          if (which == 0) {
            v *= 0.125f;  // fold 1/sqrt(64)
            qbuf[(bh * SEQ + s) * HD + dh_[nn]] = f2bf(v);
          } else {
            kbuf[(bh * SEQ + s) * HD + dh_[nn]] = f2bf(v);
          }
        }
      }
    }
  } else {
    // V: transpose through per-wave LDS, then coalesced 16B stores along s.
    __syncthreads();                 // all K-loop LDS traffic complete
    ushort* T = &lds[w * 4608];      // [64 cols(dh)][72 rows(s)+pad] per wave
    #pragma unroll
    for (int i = 0; i < 4; i++) {
      #pragma unroll
      for (int nn = 0; nn < 4; nn++) {
        int cl = nn * 16 + l15;          // col_local = dh index
        int rl = i * 16 + (l4 << 2);     // row_local base (4 rows)
        ushort4 pk;
        pk.x = f2bf(acc[i][nn][0] + bias_[nn]);
        pk.y = f2bf(acc[i][nn][1] + bias_[nn]);
        pk.z = f2bf(acc[i][nn][2] + bias_[nn]);
        pk.w = f2bf(acc[i][nn][3] + bias_[nn]);
        *reinterpret_cast<ushort4*>(&T[cl * 72 + rl]) = pk;   // ds_write_b64
      }
    }
    LGKM0;
    int hU = ((n0 - 2 * DMODEL) >> 6) + wn;    // uniform head for this wave
    int rowbase = m0 + wm * 64;
    #pragma unroll
    for (int c = 0; c < 8; c++) {
      uint4 vv = *reinterpret_cast<const uint4*>(&T[l * 72 + c * 8]);
      int R = rowbase + c * 8;
      int b0 = R / SEQ;
      int b7 = (R + 7) / SEQ;
      if (b0 == b7) {
        int s0 = R - b0 * SEQ;
        size_t addr = (((size_t)b0 * NH + hU) * HD + l) * SP + s0;
        *reinterpret_cast<uint4*>(vbuf + addr) = vv;   // 16B contiguous in s
      } else {
        const ushort* pv = reinterpret_cast<const ushort*>(&vv);
        #pragma unroll
        for (int e = 0; e < 8; e++) {
          int row = R + e;
          int bb = row / SEQ, ss = row - bb * SEQ;
          vbuf[(((size_t)bb * NH + hU) * HD + l) * SP + ss] = pv[e];
        }
      }
    }
  }
#undef ALOAD
#undef ACVTW
#undef STAGE_B
#undef LOADFRAG
#undef MFMA16
}

// ---------------- fused windowed attention (K/V resident in registers) ------
// block = (b, head-group of 4); wave = head. Each wave loads its head's FULL
// K and V into 160 VGPRs ONCE (fragments are strip-invariant in swapped-QK
// form), then iterates all 10 strips reusing them. launch_bounds(256,2).
#define AH 4
__global__ __launch_bounds__(256, 2)
void attn_kernel(const ushort* __restrict__ qbuf, const ushort* __restrict__ kbuf,
                 const ushort* __restrict__ vbuf, const float* __restrict__ mask,
                 const float* __restrict__ rbias, float* __restrict__ out) {
  __shared__ __align__(16) ushort plds[AH][16][SP + 8];  // 21 KB

  int id = blockIdx.x;
  int xcd = id & 7;
  int j = id >> 3;                 // 0..383
  int b = xcd + 8 * (j / 3);       // b % 8 == xcd
  int hg = j % 3;

  int tid = threadIdx.x;
  int lane = tid & 63, w = tid >> 6;
  int h = hg * AH + w;             // wave -> head
  int l15 = lane & 15, l4 = lane >> 4;
  int bh = b * NH + h;

  const ushort* qp = qbuf + (size_t)bh * SEQ * HD;
  const ushort* kp = kbuf + (size_t)bh * SEQ * HD;
  const ushort* vp = vbuf + (size_t)bh * HD * SP;
  const float* mbase = mask + (size_t)b * SEQ * SEQ;
  const float* rbase = rbias + (size_t)h * SEQ * RBS;

  // ---- load the head's FULL K into registers (strip-invariant) ----
  uint4 kfa[10], kfb[10];
  #pragma unroll
  for (int ct = 0; ct < 5; ct++) {
    int krow = ct * 16 + l15;            // <= 79 < SEQ
    kfa[2 * ct]     = *reinterpret_cast<const uint4*>(kp + krow * HD + l4 * 8);
    kfa[2 * ct + 1] = *reinterpret_cast<const uint4*>(kp + krow * HD + 32 + l4 * 8);
  }
  #pragma unroll
  for (int ct = 5; ct < 10; ct++) {
    int krow = ct * 16 + l15;
    if (krow >= SEQ) krow = 0;           // clamp: masked via -3e38 init
    kfb[2 * (ct - 5)]     = *reinterpret_cast<const uint4*>(kp + krow * HD + l4 * 8);
    kfb[2 * (ct - 5) + 1] = *reinterpret_cast<const uint4*>(kp + krow * HD + 32 + l4 * 8);
  }
  // ---- load the head's FULL V^T into registers (strip-invariant) ----
  uint4 vba[10], vbb[10];
  #pragma unroll
  for (int t = 0; t < 10; t++) {
    int ntl = t / 5, ks = t % 5;
    vba[t] = *reinterpret_cast<const uint4*>(
        vp + (ntl * 16 + l15) * SP + ks * 32 + l4 * 8);
  }
  #pragma unroll
  for (int t = 0; t < 10; t++) {
    int ntl = 2 + t / 5, ks = t % 5;
    vbb[t] = *reinterpret_cast<const uint4*>(
        vp + (ntl * 16 + l15) * SP + ks * 32 + l4 * 8);
  }

  // ---- strip loop: K/V stay resident; only Q/mask/rbias stream ----
  #pragma unroll 1
  for (int strip = 0; strip < 10; strip++) {
    int r0 = strip * 16;
    int qi = r0 + l15;
    int qc = (qi < SEQ) ? qi : (SEQ - 1);
    bool qok = (qi < SEQ);
    const float* mrow = mbase + (size_t)qc * SEQ;
    const float* rp = rbase + (size_t)qc * RBS;

    // Q fragment (B-operand, col = qi)
    bf16x8 qf0, qf1;
    if (qok) {
      qf0 = *reinterpret_cast<const bf16x8*>(qp + qi * HD + l4 * 8);
      qf1 = *reinterpret_cast<const bf16x8*>(qp + qi * HD + 32 + l4 * 8);
    } else {
      uint4 z = make_uint4(0, 0, 0, 0);
      qf0 = *reinterpret_cast<bf16x8*>(&z);
      qf1 = *reinterpret_cast<bf16x8*>(&z);
    }

    // init accumulators with mask + rel bias (-3e38 where masked)
    f32x4 sc[10];
    #pragma unroll
    for (int ct = 0; ct < 9; ct++) {
      int kb = ct * 16 + l4 * 4;
      f32x4u rb = *reinterpret_cast<const f32x4u*>(rp + kb);
      f32x4u mk = *reinterpret_cast<const f32x4u*>(mrow + kb);
      #pragma unroll
      for (int r = 0; r < 4; r++)
        sc[ct][r] = qok ? (mk[r] + rb[r]) : -3e38f;
    }
    {
      float iv = (l4 == 0 && qok) ? (mrow[144] + rp[144]) : -3e38f;
      sc[9][0] = iv; sc[9][1] = -3e38f; sc[9][2] = -3e38f; sc[9][3] = -3e38f;
    }

    // QK^T from resident K registers
    #pragma unroll
    for (int ct = 0; ct < 5; ct++) {
      sc[ct] = __builtin_amdgcn_mfma_f32_16x16x32_bf16(
          *reinterpret_cast<bf16x8*>(&kfa[2 * ct]), qf0, sc[ct], 0, 0, 0);
      sc[ct] = __builtin_amdgcn_mfma_f32_16x16x32_bf16(
          *reinterpret_cast<bf16x8*>(&kfa[2 * ct + 1]), qf1, sc[ct], 0, 0, 0);
    }
    #pragma unroll
    for (int ct = 5; ct < 10; ct++) {
      sc[ct] = __builtin_amdgcn_mfma_f32_16x16x32_bf16(
          *reinterpret_cast<bf16x8*>(&kfb[2 * (ct - 5)]), qf0, sc[ct], 0, 0, 0);
      sc[ct] = __builtin_amdgcn_mfma_f32_16x16x32_bf16(
          *reinterpret_cast<bf16x8*>(&kfb[2 * (ct - 5) + 1]), qf1, sc[ct], 0, 0, 0);
    }

    // softmax over ki
    float mx = -3e38f;
    #pragma unroll
    for (int ct = 0; ct < 10; ct++)
      #pragma unroll
      for (int r = 0; r < 4; r++) mx = fmaxf(mx, sc[ct][r]);
    mx = fmaxf(mx, __shfl_xor(mx, 16, 64));
    mx = fmaxf(mx, __shfl_xor(mx, 32, 64));
    float sum = 0.f;
    #pragma unroll
    for (int ct = 0; ct < 10; ct++)
      #pragma unroll
      for (int r = 0; r < 4; r++) {
        float p = __expf(sc[ct][r] - mx);
        sc[ct][r] = p;
        sum += p;
      }
    sum += __shfl_xor(sum, 16, 64);
    sum += __shfl_xor(sum, 32, 64);
    float inv = 1.f / sum;

    // P (bf16) to per-wave LDS (C-layout -> A-layout transpose)
    #pragma unroll
    for (int ct = 0; ct < 10; ct++) {
      ushort4 pk;
      pk.x = f2bf(sc[ct][0] * inv);
      pk.y = f2bf(sc[ct][1] * inv);
      pk.z = f2bf(sc[ct][2] * inv);
      pk.w = f2bf(sc[ct][3] * inv);
      *reinterpret_cast<ushort4*>(&plds[w][l15][ct * 16 + l4 * 4]) = pk;
    }

    // PV from resident V registers
    #pragma unroll
    for (int ntl = 0; ntl < 2; ntl++) {
      f32x4 pacc;
      #pragma unroll
      for (int e = 0; e < 4; e++) pacc[e] = 0.f;
      #pragma unroll
      for (int ks = 0; ks < 5; ks++) {
        bf16x8 pa = *reinterpret_cast<const bf16x8*>(
            &plds[w][l15][ks * 32 + l4 * 8]);
        pacc = __builtin_amdgcn_mfma_f32_16x16x32_bf16(
            pa, *reinterpret_cast<bf16x8*>(&vba[ntl * 5 + ks]), pacc, 0, 0, 0);
      }
      #pragma unroll
      for (int r = 0; r < 4; r++) {
        int s = r0 + l4 * 4 + r;
        if (s < SEQ)
          out[((size_t)b * SEQ + s) * DMODEL + h * HD + ntl * 16 + l15] = pacc[r];
      }
    }
    #pragma unroll
    for (int ntl = 2; ntl < 4; ntl++) {
      f32x4 pacc;
      #pragma unroll
      for (int e = 0; e < 4; e++) pacc[e] = 0.f;
      #pragma unroll
      for (int ks = 0; ks < 5; ks++) {
        bf16x8 pa = *reinterpret_cast<const bf16x8*>(
            &plds[w][l15][ks * 32 + l4 * 8]);
        pacc = __builtin_amdgcn_mfma_f32_16x16x32_bf16(
            pa, *reinterpret_cast<bf16x8*>(&vbb[(ntl - 2) * 5 + ks]), pacc, 0, 0, 0);
      }
      #pragma unroll
      for (int r = 0; r < 4; r++) {
        int s = r0 + l4 * 4 + r;
        if (s < SEQ)
          out[((size_t)b * SEQ + s) * DMODEL + h * HD + ntl * 16 + l15] = pacc[r];
      }
    }
  }
}

extern "C" void kernel_launch(void* const* d_in, const int* in_sizes, int n_in,
                              void* d_out, int out_size, void* d_ws, size_t ws_size,
                              hipStream_t stream) {
  const float* x    = (const float*)d_in[0];
  const float* mask = (const float*)d_in[1];
  const float* Wq   = (const float*)d_in[2];
  const float* bq   = (const float*)d_in[3];
  const float* Wk   = (const float*)d_in[4];
  const float* Wv   = (const float*)d_in[5];
  const float* bv   = (const float*)d_in[6];
  const float* tbl  = (const float*)d_in[7];
  float* out = (float*)d_out;

  char* ws = (char*)d_ws;
  ushort* Wt = (ushort*)ws;                         // 3,538,944 B
  size_t off = (size_t)NTOT * DMODEL * 2;
  ushort* qbuf = (ushort*)(ws + off); off += (size_t)BDIM * NH * SEQ * HD * 2;
  ushort* kbuf = (ushort*)(ws + off); off += (size_t)BDIM * NH * SEQ * HD * 2;
  ushort* vbuf = (ushort*)(ws + off); off += (size_t)BDIM * NH * HD * SP * 2;
  float*  rbias = (float*)(ws + off); off += (size_t)NH * SEQ * RBS * 4 + 64;
  // ~485 MB of d_ws

  prep_w<<<(NTOT * DMODEL + 255) / 256, 256, 0, stream>>>(Wq, Wk, Wv, Wt);
  zero_vpad<<<(BDIM * NH * HD * (SP - SEQ) + 255) / 256, 256, 0, stream>>>(vbuf);
  rel_prep<<<(NH * SEQ * RBS + 255) / 256, 256, 0, stream>>>(tbl, rbias);

  qkv_gemm<<<GNWG, 512, 0, stream>>>(x, Wt, bq, bv, qbuf, kbuf, vbuf);

  attn_kernel<<<BDIM * 3, 256, 0, stream>>>(qbuf, kbuf, vbuf, mask, rbias, out);
}

// Round 20
// 1230.722 us; speedup vs baseline: 1.0921x; 1.0921x over previous
//
#include <hip/hip_runtime.h>
#include <hip/hip_bf16.h>

typedef __bf16 bf16x8 __attribute__((ext_vector_type(8)));
typedef float f32x4 __attribute__((ext_vector_type(4)));
typedef float f32x4u __attribute__((ext_vector_type(4), aligned(4)));

#define NH 12
#define HD 64
#define SEQ 145
#define SP 160
#define DMODEL 768
#define NTOT 2304
#define BDIM 1024
#define RBS 148   // rbias padded row stride (4-aligned float4 rows)

// f32 -> bf16 RNE
__device__ __forceinline__ ushort f2bf(float f) {
  union { float f; uint u; } a; a.f = f;
  uint u = a.u;
  return (ushort)((u + 0x7FFFu + ((u >> 16) & 1u)) >> 16);
}

__device__ __forceinline__ int relidx(int qi, int ki) {
  if (ki == 0) return (qi == 0) ? 531 : 530;
  if (qi == 0) return 529;
  int q = qi - 1, k = ki - 1;
  int qh = q / 12, qw = q - qh * 12;
  int kh = k / 12, kw = k - kh * 12;
  return (qh - kh + 11) * 23 + (qw - kw + 11);
}

// async global->LDS, 16B per lane; lds dest = wave-uniform base + lane*16
__device__ __forceinline__ void gload_lds16(const ushort* g, ushort* l) {
  __builtin_amdgcn_global_load_lds(
      (const __attribute__((address_space(1))) void*)g,
      (__attribute__((address_space(3))) void*)l, 16, 0, 0);
}

#define VMCNT(n) do { asm volatile("s_waitcnt vmcnt(" #n ")" ::: "memory"); \
                      __builtin_amdgcn_sched_barrier(0); } while (0)

// ---------------- prep: Wt[n][k] = W_sel[k][n%768] as bf16 ----------------
__global__ void prep_w(const float* __restrict__ Wq, const float* __restrict__ Wk,
                       const float* __restrict__ Wv, ushort* __restrict__ Wt) {
  int i = blockIdx.x * 256 + threadIdx.x;
  if (i >= NTOT * DMODEL) return;
  int n = i / DMODEL, k = i - n * DMODEL;
  const float* W = (n < DMODEL) ? Wq : (n < 2 * DMODEL ? Wk : Wv);
  int c = n % DMODEL;
  Wt[i] = f2bf(W[k * DMODEL + c]);
}

// ---------------- x f32 -> bf16 (into d_out scratch) ----------------
__global__ void x2bf(const float* __restrict__ x, ushort* __restrict__ xb) {
  const size_t total = (size_t)BDIM * SEQ * DMODEL;
  size_t i = ((size_t)blockIdx.x * 256 + threadIdx.x) * 8;
  if (i >= total) return;
  float4 a = *reinterpret_cast<const float4*>(x + i);
  float4 c = *reinterpret_cast<const float4*>(x + i + 4);
  uint4 o;
  o.x = (uint)f2bf(a.x) | ((uint)f2bf(a.y) << 16);
  o.y = (uint)f2bf(a.z) | ((uint)f2bf(a.w) << 16);
  o.z = (uint)f2bf(c.x) | ((uint)f2bf(c.y) << 16);
  o.w = (uint)f2bf(c.z) | ((uint)f2bf(c.w) << 16);
  *reinterpret_cast<uint4*>(xb + i) = o;
}

// ---------------- zero pad region of transposed V buffer ----------------
__global__ void zero_vpad(ushort* __restrict__ vbuf) {
  int i = blockIdx.x * 256 + threadIdx.x;
  const int total = BDIM * NH * HD * (SP - SEQ);
  if (i >= total) return;
  int s = SEQ + i % (SP - SEQ);
  int row = i / (SP - SEQ);
  vbuf[(size_t)row * SP + s] = 0;
}

// ---------------- rel bias table: rbias[h][qi][ki], row stride RBS ----------------
__global__ void rel_prep(const float* __restrict__ tbl, float* __restrict__ rbias) {
  int i = blockIdx.x * 256 + threadIdx.x;
  if (i >= NH * SEQ * RBS) return;
  int h = i / (SEQ * RBS);
  int rem = i - h * SEQ * RBS;
  int qi = rem / RBS, ki = rem - qi * RBS;
  rbias[i] = (ki < SEQ) ? tbl[relidx(qi, ki) * NH + h] : 0.f;
}

// ---------------- fused QKV GEMM: [148480,768] x [768,2304] ----------------
// 128x256 tile, 8 waves (2x4), per-wave 64x64; BK=32 TRIPLE-buffered (72 KB
// LDS -> 2 blocks/CU). Stage t+2 while computing t, vmcnt(3). V-epilogue
// transposes through per-wave LDS so global stores are coalesced 16B.
#define GNT 9
#define GNWG 10440   // 1160 * 9
#define NKT 24       // 768 / 32

__global__ __launch_bounds__(512, 4)
void qkv_gemm(const ushort* __restrict__ xb, const ushort* __restrict__ Wt,
              const float* __restrict__ bq, const float* __restrict__ bv,
              ushort* __restrict__ qbuf, ushort* __restrict__ kbuf,
              ushort* __restrict__ vbuf) {
  // A[3][4096] at 0; B[3][8192] at 12288 (ushort indices). 72 KB total.
  // After the K-loop this array is reused as 8 x 4608-ushort per-wave
  // transpose scratch (8*9216 B = 73728 B, exact fit).
  __shared__ __align__(16) ushort lds[36864];

  int bid = blockIdx.x;
  int logical = (bid & 7) * 1305 + (bid >> 3);   // 10440 % 8 == 0, bijective
  int mt = logical / GNT, nt = logical - (logical / GNT) * GNT;
  int m0 = mt * 128, n0 = nt * 256;

  int tid = threadIdx.x;
  int l = tid & 63, w = tid >> 6;
  int wm = w >> 2, wn = w & 3;          // 2 x 4 wave grid
  int l15 = l & 15, l4 = l >> 4;
  int rslot = l4 ^ ((l15 >> 1) & 3);    // read-side swizzle (BK=32: 4 slots)

  // staging: thread t -> row (t>>2), stored slot (t&3); src chunk inverse-swz
  int srow = tid >> 2;                  // 0..127
  int schunk = (tid & 3) ^ ((tid >> 3) & 3);
  const ushort* aSrc  = xb + (size_t)(m0 + srow) * DMODEL + schunk * 8;
  const ushort* bSrc0 = Wt + (size_t)(n0 + srow) * DMODEL + schunk * 8;
  const ushort* bSrc1 = Wt + (size_t)(n0 + 128 + srow) * DMODEL + schunk * 8;
  int wdst = w << 9;   // w*512 ushorts (wave-contiguous dest)

#define STAGE(db, kof) do { \
    gload_lds16(aSrc  + (kof), &lds[(db) * 4096 + wdst]); \
    gload_lds16(bSrc0 + (kof), &lds[12288 + (db) * 8192 + wdst]); \
    gload_lds16(bSrc1 + (kof), &lds[12288 + (db) * 8192 + 4096 + wdst]); \
  } while (0)

  f32x4 acc[4][4];
  #pragma unroll
  for (int m = 0; m < 4; m++)
    #pragma unroll
    for (int n = 0; n < 4; n++)
      #pragma unroll
      for (int e = 0; e < 4; e++) acc[m][n][e] = 0.f;

  bf16x8 af[4], bfv[4];

#define LOADFRAG(db) do { \
    int ab_ = (db) * 4096, bb_ = 12288 + (db) * 8192; \
    _Pragma("unroll") \
    for (int i_ = 0; i_ < 4; i_++) \
      af[i_] = *reinterpret_cast<const bf16x8*>( \
          &lds[ab_ + ((wm * 64 + i_ * 16 + l15) << 5) + rslot * 8]); \
    _Pragma("unroll") \
    for (int n_ = 0; n_ < 4; n_++) \
      bfv[n_] = *reinterpret_cast<const bf16x8*>( \
          &lds[bb_ + ((wn * 64 + n_ * 16 + l15) << 5) + rslot * 8]); \
  } while (0)
#define MFMA16() do { \
    __builtin_amdgcn_s_setprio(1); \
    _Pragma("unroll") \
    for (int i_ = 0; i_ < 4; i_++) \
      _Pragma("unroll") \
      for (int n_ = 0; n_ < 4; n_++) \
        acc[i_][n_] = __builtin_amdgcn_mfma_f32_16x16x32_bf16( \
            af[i_], bfv[n_], acc[i_][n_], 0, 0, 0); \
    __builtin_amdgcn_s_setprio(0); \
  } while (0)

  // prologue: stage tiles 0 and 1; wait tile 0 only (tile 1 stays in flight)
  STAGE(0, 0);
  STAGE(1, 32);
  VMCNT(3);
  __builtin_amdgcn_s_barrier();

  #pragma unroll
  for (int t = 0; t < NKT; ++t) {
    int cur = t % 3, nx2 = (t + 2) % 3;
    if (t + 2 < NKT) STAGE(nx2, (t + 2) * 32);   // deep prefetch (tile t+2)
    LOADFRAG(cur);                                // published at t-1's barrier
    MFMA16();                                     // lgkmcnt auto-inserted
    if (t < NKT - 1) {
      if (t + 2 < NKT) { VMCNT(3); }              // retire t+1; t+2 in flight
      else             { VMCNT(0); }              // tail: retire final tile
      __builtin_amdgcn_s_barrier();               // publish t+1
    }
  }

  // ---- epilogue ----
  int which = n0 / DMODEL;
  int h_[4], dh_[4];
  float bias_[4];
  #pragma unroll
  for (int nn = 0; nn < 4; nn++) {
    int col = n0 + wn * 64 + nn * 16 + l15;
    int hcol = col - which * DMODEL;
    h_[nn] = hcol >> 6; dh_[nn] = hcol & 63;
    bias_[nn] = (which == 0) ? bq[hcol] : (which == 2 ? bv[hcol] : 0.f);
  }

  if (which != 2) {
    // q / k: coalesced-enough direct stores (dh consecutive per l15)
    #pragma unroll
    for (int i = 0; i < 4; i++) {
      #pragma unroll
      for (int r = 0; r < 4; r++) {
        int row = m0 + wm * 64 + i * 16 + (l4 << 2) + r;
        int b = row / SEQ;
        int s = row - b * SEQ;
        #pragma unroll
        for (int nn = 0; nn < 4; nn++) {
          float v = acc[i][nn][r] + bias_[nn];
          size_t bh = (size_t)b * NH + h_[nn];
          if (which == 0) {
            v *= 0.125f;  // fold 1/sqrt(64)
            qbuf[(bh * SEQ + s) * HD + dh_[nn]] = f2bf(v);
          } else {
            kbuf[(bh * SEQ + s) * HD + dh_[nn]] = f2bf(v);
          }
        }
      }
    }
  } else {
    // V: transpose through per-wave LDS, then coalesced 16B stores along s.
    __syncthreads();                 // all K-loop ds_reads complete; LDS free
    ushort* T = &lds[w * 4608];      // [64 cols(dh)][72 rows(s)+pad] per wave
    #pragma unroll
    for (int i = 0; i < 4; i++) {
      #pragma unroll
      for (int nn = 0; nn < 4; nn++) {
        int cl = nn * 16 + l15;          // col_local = dh index
        int rl = i * 16 + (l4 << 2);     // row_local base (4 rows)
        ushort4 pk;
        pk.x = f2bf(acc[i][nn][0] + bias_[nn]);
        pk.y = f2bf(acc[i][nn][1] + bias_[nn]);
        pk.z = f2bf(acc[i][nn][2] + bias_[nn]);
        pk.w = f2bf(acc[i][nn][3] + bias_[nn]);
        *reinterpret_cast<ushort4*>(&T[cl * 72 + rl]) = pk;   // ds_write_b64
      }
    }
    asm volatile("s_waitcnt lgkmcnt(0)" ::: "memory");
    __builtin_amdgcn_sched_barrier(0);
    int hU = ((n0 - 2 * DMODEL) >> 6) + wn;    // uniform head for this wave
    int rowbase = m0 + wm * 64;
    #pragma unroll
    for (int c = 0; c < 8; c++) {
      uint4 vv = *reinterpret_cast<const uint4*>(&T[l * 72 + c * 8]);
      int R = rowbase + c * 8;
      int b0 = R / SEQ;
      int b7 = (R + 7) / SEQ;
      if (b0 == b7) {
        int s0 = R - b0 * SEQ;
        size_t addr = (((size_t)b0 * NH + hU) * HD + l) * SP + s0;
        *reinterpret_cast<uint4*>(vbuf + addr) = vv;   // 16B contiguous in s
      } else {
        const ushort* pv = reinterpret_cast<const ushort*>(&vv);
        #pragma unroll
        for (int e = 0; e < 8; e++) {
          int row = R + e;
          int bb = row / SEQ, ss = row - bb * SEQ;
          vbuf[(((size_t)bb * NH + hU) * HD + l) * SP + ss] = pv[e];
        }
      }
    }
  }
#undef STAGE
#undef LOADFRAG
#undef MFMA16
}

// ---------------- fused windowed attention (K/V resident in registers) ------
// block = (b, head-group of 4); wave = head. Each wave loads its head's FULL
// K and V into 160 VGPRs ONCE (fragments are strip-invariant in swapped-QK
// form), then iterates all 10 strips reusing them: per-strip loads drop to
// Q+mask+rbias only, and K/V HBM re-reads drop ~10x. launch_bounds(256,2):
// VGPR cap 256 >= ~235 needed, no spill. XCD b-affinity: b % 8 == xcd.
#define AH 4
__global__ __launch_bounds__(256, 2)
void attn_kernel(const ushort* __restrict__ qbuf, const ushort* __restrict__ kbuf,
                 const ushort* __restrict__ vbuf, const float* __restrict__ mask,
                 const float* __restrict__ rbias, float* __restrict__ out) {
  __shared__ __align__(16) ushort plds[AH][16][SP + 8];  // 21 KB

  int id = blockIdx.x;
  int xcd = id & 7;
  int j = id >> 3;                 // 0..383
  int b = xcd + 8 * (j / 3);       // b % 8 == xcd
  int hg = j % 3;

  int tid = threadIdx.x;
  int lane = tid & 63, w = tid >> 6;
  int h = hg * AH + w;             // wave -> head
  int l15 = lane & 15, l4 = lane >> 4;
  int bh = b * NH + h;

  const ushort* qp = qbuf + (size_t)bh * SEQ * HD;
  const ushort* kp = kbuf + (size_t)bh * SEQ * HD;
  const ushort* vp = vbuf + (size_t)bh * HD * SP;
  const float* mbase = mask + (size_t)b * SEQ * SEQ;
  const float* rbase = rbias + (size_t)h * SEQ * RBS;

  // ---- load the head's FULL K into registers (strip-invariant) ----
  uint4 kfa[10], kfb[10];
  #pragma unroll
  for (int ct = 0; ct < 5; ct++) {
    int krow = ct * 16 + l15;            // <= 79 < SEQ
    kfa[2 * ct]     = *reinterpret_cast<const uint4*>(kp + krow * HD + l4 * 8);
    kfa[2 * ct + 1] = *reinterpret_cast<const uint4*>(kp + krow * HD + 32 + l4 * 8);
  }
  #pragma unroll
  for (int ct = 5; ct < 10; ct++) {
    int krow = ct * 16 + l15;
    if (krow >= SEQ) krow = 0;           // clamp: masked via -3e38 init
    kfb[2 * (ct - 5)]     = *reinterpret_cast<const uint4*>(kp + krow * HD + l4 * 8);
    kfb[2 * (ct - 5) + 1] = *reinterpret_cast<const uint4*>(kp + krow * HD + 32 + l4 * 8);
  }
  // ---- load the head's FULL V^T into registers (strip-invariant) ----
  uint4 vba[10], vbb[10];
  #pragma unroll
  for (int t = 0; t < 10; t++) {
    int ntl = t / 5, ks = t % 5;
    vba[t] = *reinterpret_cast<const uint4*>(
        vp + (ntl * 16 + l15) * SP + ks * 32 + l4 * 8);
  }
  #pragma unroll
  for (int t = 0; t < 10; t++) {
    int ntl = 2 + t / 5, ks = t % 5;
    vbb[t] = *reinterpret_cast<const uint4*>(
        vp + (ntl * 16 + l15) * SP + ks * 32 + l4 * 8);
  }

  // ---- strip loop: K/V stay resident; only Q/mask/rbias stream ----
  #pragma unroll 1
  for (int strip = 0; strip < 10; strip++) {
    int r0 = strip * 16;
    int qi = r0 + l15;
    int qc = (qi < SEQ) ? qi : (SEQ - 1);
    bool qok = (qi < SEQ);
    const float* mrow = mbase + (size_t)qc * SEQ;
    const float* rp = rbase + (size_t)qc * RBS;

    // Q fragment (B-operand, col = qi)
    bf16x8 qf0, qf1;
    if (qok) {
      qf0 = *reinterpret_cast<const bf16x8*>(qp + qi * HD + l4 * 8);
      qf1 = *reinterpret_cast<const bf16x8*>(qp + qi * HD + 32 + l4 * 8);
    } else {
      uint4 z = make_uint4(0, 0, 0, 0);
      qf0 = *reinterpret_cast<bf16x8*>(&z);
      qf1 = *reinterpret_cast<bf16x8*>(&z);
    }

    // init accumulators with mask + rel bias (-3e38 where masked)
    f32x4 sc[10];
    #pragma unroll
    for (int ct = 0; ct < 9; ct++) {
      int kb = ct * 16 + l4 * 4;
      f32x4u rb = *reinterpret_cast<const f32x4u*>(rp + kb);
      f32x4u mk = *reinterpret_cast<const f32x4u*>(mrow + kb);
      #pragma unroll
      for (int r = 0; r < 4; r++)
        sc[ct][r] = qok ? (mk[r] + rb[r]) : -3e38f;
    }
    {
      float iv = (l4 == 0 && qok) ? (mrow[144] + rp[144]) : -3e38f;
      sc[9][0] = iv; sc[9][1] = -3e38f; sc[9][2] = -3e38f; sc[9][3] = -3e38f;
    }

    // QK^T from resident K registers
    #pragma unroll
    for (int ct = 0; ct < 5; ct++) {
      sc[ct] = __builtin_amdgcn_mfma_f32_16x16x32_bf16(
          *reinterpret_cast<bf16x8*>(&kfa[2 * ct]), qf0, sc[ct], 0, 0, 0);
      sc[ct] = __builtin_amdgcn_mfma_f32_16x16x32_bf16(
          *reinterpret_cast<bf16x8*>(&kfa[2 * ct + 1]), qf1, sc[ct], 0, 0, 0);
    }
    #pragma unroll
    for (int ct = 5; ct < 10; ct++) {
      sc[ct] = __builtin_amdgcn_mfma_f32_16x16x32_bf16(
          *reinterpret_cast<bf16x8*>(&kfb[2 * (ct - 5)]), qf0, sc[ct], 0, 0, 0);
      sc[ct] = __builtin_amdgcn_mfma_f32_16x16x32_bf16(
          *reinterpret_cast<bf16x8*>(&kfb[2 * (ct - 5) + 1]), qf1, sc[ct], 0, 0, 0);
    }

    // softmax over ki
    float mx = -3e38f;
    #pragma unroll
    for (int ct = 0; ct < 10; ct++)
      #pragma unroll
      for (int r = 0; r < 4; r++) mx = fmaxf(mx, sc[ct][r]);
    mx = fmaxf(mx, __shfl_xor(mx, 16, 64));
    mx = fmaxf(mx, __shfl_xor(mx, 32, 64));
    float sum = 0.f;
    #pragma unroll
    for (int ct = 0; ct < 10; ct++)
      #pragma unroll
      for (int r = 0; r < 4; r++) {
        float p = __expf(sc[ct][r] - mx);
        sc[ct][r] = p;
        sum += p;
      }
    sum += __shfl_xor(sum, 16, 64);
    sum += __shfl_xor(sum, 32, 64);
    float inv = 1.f / sum;

    // P (bf16) to per-wave LDS (C-layout -> A-layout transpose)
    #pragma unroll
    for (int ct = 0; ct < 10; ct++) {
      ushort4 pk;
      pk.x = f2bf(sc[ct][0] * inv);
      pk.y = f2bf(sc[ct][1] * inv);
      pk.z = f2bf(sc[ct][2] * inv);
      pk.w = f2bf(sc[ct][3] * inv);
      *reinterpret_cast<ushort4*>(&plds[w][l15][ct * 16 + l4 * 4]) = pk;
    }

    // PV from resident V registers
    #pragma unroll
    for (int ntl = 0; ntl < 2; ntl++) {
      f32x4 pacc;
      #pragma unroll
      for (int e = 0; e < 4; e++) pacc[e] = 0.f;
      #pragma unroll
      for (int ks = 0; ks < 5; ks++) {
        bf16x8 pa = *reinterpret_cast<const bf16x8*>(
            &plds[w][l15][ks * 32 + l4 * 8]);
        pacc = __builtin_amdgcn_mfma_f32_16x16x32_bf16(
            pa, *reinterpret_cast<bf16x8*>(&vba[ntl * 5 + ks]), pacc, 0, 0, 0);
      }
      #pragma unroll
      for (int r = 0; r < 4; r++) {
        int s = r0 + l4 * 4 + r;
        if (s < SEQ)
          out[((size_t)b * SEQ + s) * DMODEL + h * HD + ntl * 16 + l15] = pacc[r];
      }
    }
    #pragma unroll
    for (int ntl = 2; ntl < 4; ntl++) {
      f32x4 pacc;
      #pragma unroll
      for (int e = 0; e < 4; e++) pacc[e] = 0.f;
      #pragma unroll
      for (int ks = 0; ks < 5; ks++) {
        bf16x8 pa = *reinterpret_cast<const bf16x8*>(
            &plds[w][l15][ks * 32 + l4 * 8]);
        pacc = __builtin_amdgcn_mfma_f32_16x16x32_bf16(
            pa, *reinterpret_cast<bf16x8*>(&vbb[(ntl - 2) * 5 + ks]), pacc, 0, 0, 0);
      }
      #pragma unroll
      for (int r = 0; r < 4; r++) {
        int s = r0 + l4 * 4 + r;
        if (s < SEQ)
          out[((size_t)b * SEQ + s) * DMODEL + h * HD + ntl * 16 + l15] = pacc[r];
      }
    }
  }
}

extern "C" void kernel_launch(void* const* d_in, const int* in_sizes, int n_in,
                              void* d_out, int out_size, void* d_ws, size_t ws_size,
                              hipStream_t stream) {
  const float* x    = (const float*)d_in[0];
  const float* mask = (const float*)d_in[1];
  const float* Wq   = (const float*)d_in[2];
  const float* bq   = (const float*)d_in[3];
  const float* Wk   = (const float*)d_in[4];
  const float* Wv   = (const float*)d_in[5];
  const float* bv   = (const float*)d_in[6];
  const float* tbl  = (const float*)d_in[7];
  float* out = (float*)d_out;

  char* ws = (char*)d_ws;
  ushort* Wt = (ushort*)ws;                         // 3,538,944 B
  size_t off = (size_t)NTOT * DMODEL * 2;
  ushort* qbuf = (ushort*)(ws + off); off += (size_t)BDIM * NH * SEQ * HD * 2;
  ushort* kbuf = (ushort*)(ws + off); off += (size_t)BDIM * NH * SEQ * HD * 2;
  ushort* vbuf = (ushort*)(ws + off); off += (size_t)BDIM * NH * HD * SP * 2;
  float*  rbias = (float*)(ws + off); off += (size_t)NH * SEQ * RBS * 4 + 64;
  // ~713 MB of d_ws

  // bf16 x lives in d_out scratch (456 MB f32 out >= 228 MB bf16 x);
  // attn_kernel later overwrites every element of d_out.
  ushort* xbuf = (ushort*)d_out;

  prep_w<<<(NTOT * DMODEL + 255) / 256, 256, 0, stream>>>(Wq, Wk, Wv, Wt);
  zero_vpad<<<(BDIM * NH * HD * (SP - SEQ) + 255) / 256, 256, 0, stream>>>(vbuf);
  rel_prep<<<(NH * SEQ * RBS + 255) / 256, 256, 0, stream>>>(tbl, rbias);
  {
    size_t total = (size_t)BDIM * SEQ * DMODEL;
    x2bf<<<(int)(total / 8 / 256), 256, 0, stream>>>(x, xbuf);
  }

  qkv_gemm<<<GNWG, 512, 0, stream>>>(xbuf, Wt, bq, bv, qbuf, kbuf, vbuf);

  attn_kernel<<<BDIM * 3, 256, 0, stream>>>(qbuf, kbuf, vbuf, mask, rbias, out);
}

// Round 21
// 1199.567 us; speedup vs baseline: 1.1205x; 1.0260x over previous
//
#include <hip/hip_runtime.h>
#include <hip/hip_bf16.h>

typedef __bf16 bf16x8 __attribute__((ext_vector_type(8)));
typedef float f32x4 __attribute__((ext_vector_type(4)));
typedef float f32x4u __attribute__((ext_vector_type(4), aligned(4)));

#define NH 12
#define HD 64
#define SEQ 145
#define SP 160
#define DMODEL 768
#define NTOT 2304
#define BDIM 1024
#define RBS 148   // rbias padded row stride (4-aligned float4 rows)

// f32 -> bf16 RNE
__device__ __forceinline__ ushort f2bf(float f) {
  union { float f; uint u; } a; a.f = f;
  uint u = a.u;
  return (ushort)((u + 0x7FFFu + ((u >> 16) & 1u)) >> 16);
}

__device__ __forceinline__ int relidx(int qi, int ki) {
  if (ki == 0) return (qi == 0) ? 531 : 530;
  if (qi == 0) return 529;
  int q = qi - 1, k = ki - 1;
  int qh = q / 12, qw = q - qh * 12;
  int kh = k / 12, kw = k - kh * 12;
  return (qh - kh + 11) * 23 + (qw - kw + 11);
}

// async global->LDS, 16B per lane; lds dest = wave-uniform base + lane*16
__device__ __forceinline__ void gload_lds16(const ushort* g, ushort* l) {
  __builtin_amdgcn_global_load_lds(
      (const __attribute__((address_space(1))) void*)g,
      (__attribute__((address_space(3))) void*)l, 16, 0, 0);
}

#define VMCNT(n) do { asm volatile("s_waitcnt vmcnt(" #n ")" ::: "memory"); \
                      __builtin_amdgcn_sched_barrier(0); } while (0)

// ---------------- merged prep: Wt transpose-cast | vbuf pad zero | rbias ----
#define NP1 6912    // (NTOT*DMODEL)/256
#define NP2 46080   // (BDIM*NH*HD*(SP-SEQ))/256
#define NP3 1006    // ceil(NH*SEQ*RBS/256)
__global__ void prep_all(const float* __restrict__ Wq, const float* __restrict__ Wk,
                         const float* __restrict__ Wv, ushort* __restrict__ Wt,
                         ushort* __restrict__ vbuf, const float* __restrict__ tbl,
                         float* __restrict__ rbias) {
  int bid = blockIdx.x;
  int tid = threadIdx.x;
  if (bid < NP1) {
    int i = bid * 256 + tid;
    int n = i / DMODEL, k = i - n * DMODEL;
    const float* W = (n < DMODEL) ? Wq : (n < 2 * DMODEL ? Wk : Wv);
    int c = n % DMODEL;
    Wt[i] = f2bf(W[k * DMODEL + c]);
  } else if (bid < NP1 + NP2) {
    int i = (bid - NP1) * 256 + tid;
    int s = SEQ + i % (SP - SEQ);
    int row = i / (SP - SEQ);
    vbuf[(size_t)row * SP + s] = 0;
  } else {
    int i = (bid - NP1 - NP2) * 256 + tid;
    if (i < NH * SEQ * RBS) {
      int h = i / (SEQ * RBS);
      int rem = i - h * SEQ * RBS;
      int qi = rem / RBS, ki = rem - qi * RBS;
      rbias[i] = (ki < SEQ) ? tbl[relidx(qi, ki) * NH + h] : 0.f;
    }
  }
}

// ---------------- x f32 -> bf16 (into d_out scratch) ----------------
__global__ void x2bf(const float* __restrict__ x, ushort* __restrict__ xb) {
  const size_t total = (size_t)BDIM * SEQ * DMODEL;
  size_t i = ((size_t)blockIdx.x * 256 + threadIdx.x) * 8;
  if (i >= total) return;
  float4 a = *reinterpret_cast<const float4*>(x + i);
  float4 c = *reinterpret_cast<const float4*>(x + i + 4);
  uint4 o;
  o.x = (uint)f2bf(a.x) | ((uint)f2bf(a.y) << 16);
  o.y = (uint)f2bf(a.z) | ((uint)f2bf(a.w) << 16);
  o.z = (uint)f2bf(c.x) | ((uint)f2bf(c.y) << 16);
  o.w = (uint)f2bf(c.z) | ((uint)f2bf(c.w) << 16);
  *reinterpret_cast<uint4*>(xb + i) = o;
}

// ---------------- fused QKV GEMM: [148480,768] x [768,2304] ----------------
// 128x256 tile, 8 waves (2x4), per-wave 64x64; BK=32 TRIPLE-buffered (72 KB
// LDS -> 2 blocks/CU). Stage t+2 while computing t, vmcnt(3). BOTH epilogues
// now transpose through per-wave LDS: q/k 64 scalar 2B stores/thread ->
// 8 coalesced 16B stores (1KB contiguous per instruction); V as before.
#define GNT 9
#define GNWG 10440   // 1160 * 9
#define NKT 24       // 768 / 32

__global__ __launch_bounds__(512, 4)
void qkv_gemm(const ushort* __restrict__ xb, const ushort* __restrict__ Wt,
              const float* __restrict__ bq, const float* __restrict__ bv,
              ushort* __restrict__ qbuf, ushort* __restrict__ kbuf,
              ushort* __restrict__ vbuf) {
  // A[3][4096] at 0; B[3][8192] at 12288 (ushort indices). 72 KB total.
  // After the K-loop: 8 x 4608-ushort per-wave transpose scratch (exact fit).
  __shared__ __align__(16) ushort lds[36864];

  int bid = blockIdx.x;
  int logical = (bid & 7) * 1305 + (bid >> 3);   // 10440 % 8 == 0, bijective
  int mt = logical / GNT, nt = logical - (logical / GNT) * GNT;
  int m0 = mt * 128, n0 = nt * 256;

  int tid = threadIdx.x;
  int l = tid & 63, w = tid >> 6;
  int wm = w >> 2, wn = w & 3;          // 2 x 4 wave grid
  int l15 = l & 15, l4 = l >> 4;
  int rslot = l4 ^ ((l15 >> 1) & 3);    // read-side swizzle (BK=32: 4 slots)

  // staging: thread t -> row (t>>2), stored slot (t&3); src chunk inverse-swz
  int srow = tid >> 2;                  // 0..127
  int schunk = (tid & 3) ^ ((tid >> 3) & 3);
  const ushort* aSrc  = xb + (size_t)(m0 + srow) * DMODEL + schunk * 8;
  const ushort* bSrc0 = Wt + (size_t)(n0 + srow) * DMODEL + schunk * 8;
  const ushort* bSrc1 = Wt + (size_t)(n0 + 128 + srow) * DMODEL + schunk * 8;
  int wdst = w << 9;   // w*512 ushorts (wave-contiguous dest)

#define STAGE(db, kof) do { \
    gload_lds16(aSrc  + (kof), &lds[(db) * 4096 + wdst]); \
    gload_lds16(bSrc0 + (kof), &lds[12288 + (db) * 8192 + wdst]); \
    gload_lds16(bSrc1 + (kof), &lds[12288 + (db) * 8192 + 4096 + wdst]); \
  } while (0)

  f32x4 acc[4][4];
  #pragma unroll
  for (int m = 0; m < 4; m++)
    #pragma unroll
    for (int n = 0; n < 4; n++)
      #pragma unroll
      for (int e = 0; e < 4; e++) acc[m][n][e] = 0.f;

  bf16x8 af[4], bfv[4];

#define LOADFRAG(db) do { \
    int ab_ = (db) * 4096, bb_ = 12288 + (db) * 8192; \
    _Pragma("unroll") \
    for (int i_ = 0; i_ < 4; i_++) \
      af[i_] = *reinterpret_cast<const bf16x8*>( \
          &lds[ab_ + ((wm * 64 + i_ * 16 + l15) << 5) + rslot * 8]); \
    _Pragma("unroll") \
    for (int n_ = 0; n_ < 4; n_++) \
      bfv[n_] = *reinterpret_cast<const bf16x8*>( \
          &lds[bb_ + ((wn * 64 + n_ * 16 + l15) << 5) + rslot * 8]); \
  } while (0)
#define MFMA16() do { \
    __builtin_amdgcn_s_setprio(1); \
    _Pragma("unroll") \
    for (int i_ = 0; i_ < 4; i_++) \
      _Pragma("unroll") \
      for (int n_ = 0; n_ < 4; n_++) \
        acc[i_][n_] = __builtin_amdgcn_mfma_f32_16x16x32_bf16( \
            af[i_], bfv[n_], acc[i_][n_], 0, 0, 0); \
    __builtin_amdgcn_s_setprio(0); \
  } while (0)

  // prologue: stage tiles 0 and 1; wait tile 0 only (tile 1 stays in flight)
  STAGE(0, 0);
  STAGE(1, 32);
  VMCNT(3);
  __builtin_amdgcn_s_barrier();

  #pragma unroll
  for (int t = 0; t < NKT; ++t) {
    int cur = t % 3, nx2 = (t + 2) % 3;
    if (t + 2 < NKT) STAGE(nx2, (t + 2) * 32);   // deep prefetch (tile t+2)
    LOADFRAG(cur);                                // published at t-1's barrier
    MFMA16();                                     // lgkmcnt auto-inserted
    if (t < NKT - 1) {
      if (t + 2 < NKT) { VMCNT(3); }              // retire t+1; t+2 in flight
      else             { VMCNT(0); }              // tail: retire final tile
      __builtin_amdgcn_s_barrier();               // publish t+1
    }
  }

  // ---- epilogue ----
  int which = n0 / DMODEL;
  float bias_[4];
  #pragma unroll
  for (int nn = 0; nn < 4; nn++) {
    int col = n0 + wn * 64 + nn * 16 + l15;
    int hcol = col - which * DMODEL;
    bias_[nn] = (which == 0) ? bq[hcol] : (which == 2 ? bv[hcol] : 0.f);
  }
  int hU = ((n0 - which * DMODEL) >> 6) + wn;   // wave-uniform head
  int rowbase = m0 + wm * 64;

  __syncthreads();                  // all K-loop LDS reads complete; LDS free
  ushort* T = &lds[w * 4608];       // per-wave 4608-ushort scratch

  if (which != 2) {
    // q / k: T[row_local 64][72] then coalesced 16B row-chunk stores.
    float scale = (which == 0) ? 0.125f : 1.f;
    #pragma unroll
    for (int i = 0; i < 4; i++)
      #pragma unroll
      for (int nn = 0; nn < 4; nn++)
        #pragma unroll
        for (int r = 0; r < 4; r++)
          T[(i * 16 + (l4 << 2) + r) * 72 + nn * 16 + l15] =
              f2bf((acc[i][nn][r] + bias_[nn]) * scale);
    asm volatile("s_waitcnt lgkmcnt(0)" ::: "memory");
    __builtin_amdgcn_sched_barrier(0);
    ushort* dst = (which == 0) ? qbuf : kbuf;
    int chunk = l & 7;
    #pragma unroll
    for (int c = 0; c < 8; c++) {
      int rl = (l >> 3) + 8 * c;
      uint4 vv = *reinterpret_cast<const uint4*>(&T[rl * 72 + chunk * 8]);
      int row = rowbase + rl;
      int bb = row / SEQ, ss = row - bb * SEQ;
      size_t addr = (((size_t)bb * NH + hU) * SEQ + ss) * HD + chunk * 8;
      *reinterpret_cast<uint4*>(dst + addr) = vv;   // 1KB contiguous / inst
    }
  } else {
    // V: T[64 cols(dh)][72 rows(s)+pad], coalesced 16B stores along s.
    #pragma unroll
    for (int i = 0; i < 4; i++) {
      #pragma unroll
      for (int nn = 0; nn < 4; nn++) {
        int cl = nn * 16 + l15;          // col_local = dh index
        int rl = i * 16 + (l4 << 2);     // row_local base (4 rows)
        ushort4 pk;
        pk.x = f2bf(acc[i][nn][0] + bias_[nn]);
        pk.y = f2bf(acc[i][nn][1] + bias_[nn]);
        pk.z = f2bf(acc[i][nn][2] + bias_[nn]);
        pk.w = f2bf(acc[i][nn][3] + bias_[nn]);
        *reinterpret_cast<ushort4*>(&T[cl * 72 + rl]) = pk;   // ds_write_b64
      }
    }
    asm volatile("s_waitcnt lgkmcnt(0)" ::: "memory");
    __builtin_amdgcn_sched_barrier(0);
    #pragma unroll
    for (int c = 0; c < 8; c++) {
      uint4 vv = *reinterpret_cast<const uint4*>(&T[l * 72 + c * 8]);
      int R = rowbase + c * 8;
      int b0 = R / SEQ;
      int b7 = (R + 7) / SEQ;
      if (b0 == b7) {
        int s0 = R - b0 * SEQ;
        size_t addr = (((size_t)b0 * NH + hU) * HD + l) * SP + s0;
        *reinterpret_cast<uint4*>(vbuf + addr) = vv;   // 16B contiguous in s
      } else {
        const ushort* pv = reinterpret_cast<const ushort*>(&vv);
        #pragma unroll
        for (int e = 0; e < 8; e++) {
          int row = R + e;
          int bb = row / SEQ, ss = row - bb * SEQ;
          vbuf[(((size_t)bb * NH + hU) * HD + l) * SP + ss] = pv[e];
        }
      }
    }
  }
#undef STAGE
#undef LOADFRAG
#undef MFMA16
}

// ---------------- fused windowed attention (K/V resident in registers) ------
// block = (b, head-group of 4); wave = head. Each wave loads its head's FULL
// K and V into 160 VGPRs ONCE (fragments are strip-invariant in swapped-QK
// form), then iterates all 10 strips reusing them. launch_bounds(256,2).
// XCD b-affinity: b % 8 == xcd.
#define AH 4
__global__ __launch_bounds__(256, 2)
void attn_kernel(const ushort* __restrict__ qbuf, const ushort* __restrict__ kbuf,
                 const ushort* __restrict__ vbuf, const float* __restrict__ mask,
                 const float* __restrict__ rbias, float* __restrict__ out) {
  __shared__ __align__(16) ushort plds[AH][16][SP + 8];  // 21 KB

  int id = blockIdx.x;
  int xcd = id & 7;
  int j = id >> 3;                 // 0..383
  int b = xcd + 8 * (j / 3);       // b % 8 == xcd
  int hg = j % 3;

  int tid = threadIdx.x;
  int lane = tid & 63, w = tid >> 6;
  int h = hg * AH + w;             // wave -> head
  int l15 = lane & 15, l4 = lane >> 4;
  int bh = b * NH + h;

  const ushort* qp = qbuf + (size_t)bh * SEQ * HD;
  const ushort* kp = kbuf + (size_t)bh * SEQ * HD;
  const ushort* vp = vbuf + (size_t)bh * HD * SP;
  const float* mbase = mask + (size_t)b * SEQ * SEQ;
  const float* rbase = rbias + (size_t)h * SEQ * RBS;

  // ---- load the head's FULL K into registers (strip-invariant) ----
  uint4 kfa[10], kfb[10];
  #pragma unroll
  for (int ct = 0; ct < 5; ct++) {
    int krow = ct * 16 + l15;            // <= 79 < SEQ
    kfa[2 * ct]     = *reinterpret_cast<const uint4*>(kp + krow * HD + l4 * 8);
    kfa[2 * ct + 1] = *reinterpret_cast<const uint4*>(kp + krow * HD + 32 + l4 * 8);
  }
  #pragma unroll
  for (int ct = 5; ct < 10; ct++) {
    int krow = ct * 16 + l15;
    if (krow >= SEQ) krow = 0;           // clamp: masked via -3e38 init
    kfb[2 * (ct - 5)]     = *reinterpret_cast<const uint4*>(kp + krow * HD + l4 * 8);
    kfb[2 * (ct - 5) + 1] = *reinterpret_cast<const uint4*>(kp + krow * HD + 32 + l4 * 8);
  }
  // ---- load the head's FULL V^T into registers (strip-invariant) ----
  uint4 vba[10], vbb[10];
  #pragma unroll
  for (int t = 0; t < 10; t++) {
    int ntl = t / 5, ks = t % 5;
    vba[t] = *reinterpret_cast<const uint4*>(
        vp + (ntl * 16 + l15) * SP + ks * 32 + l4 * 8);
  }
  #pragma unroll
  for (int t = 0; t < 10; t++) {
    int ntl = 2 + t / 5, ks = t % 5;
    vbb[t] = *reinterpret_cast<const uint4*>(
        vp + (ntl * 16 + l15) * SP + ks * 32 + l4 * 8);
  }

  // ---- strip loop: K/V stay resident; only Q/mask/rbias stream ----
  #pragma unroll 1
  for (int strip = 0; strip < 10; strip++) {
    int r0 = strip * 16;
    int qi = r0 + l15;
    int qc = (qi < SEQ) ? qi : (SEQ - 1);
    bool qok = (qi < SEQ);
    const float* mrow = mbase + (size_t)qc * SEQ;
    const float* rp = rbase + (size_t)qc * RBS;

    // Q fragment (B-operand, col = qi)
    bf16x8 qf0, qf1;
    if (qok) {
      qf0 = *reinterpret_cast<const bf16x8*>(qp + qi * HD + l4 * 8);
      qf1 = *reinterpret_cast<const bf16x8*>(qp + qi * HD + 32 + l4 * 8);
    } else {
      uint4 z = make_uint4(0, 0, 0, 0);
      qf0 = *reinterpret_cast<bf16x8*>(&z);
      qf1 = *reinterpret_cast<bf16x8*>(&z);
    }

    // init accumulators with mask + rel bias (-3e38 where masked)
    f32x4 sc[10];
    #pragma unroll
    for (int ct = 0; ct < 9; ct++) {
      int kb = ct * 16 + l4 * 4;
      f32x4u rb = *reinterpret_cast<const f32x4u*>(rp + kb);
      f32x4u mk = *reinterpret_cast<const f32x4u*>(mrow + kb);
      #pragma unroll
      for (int r = 0; r < 4; r++)
        sc[ct][r] = qok ? (mk[r] + rb[r]) : -3e38f;
    }
    {
      float iv = (l4 == 0 && qok) ? (mrow[144] + rp[144]) : -3e38f;
      sc[9][0] = iv; sc[9][1] = -3e38f; sc[9][2] = -3e38f; sc[9][3] = -3e38f;
    }

    // QK^T from resident K registers
    #pragma unroll
    for (int ct = 0; ct < 5; ct++) {
      sc[ct] = __builtin_amdgcn_mfma_f32_16x16x32_bf16(
          *reinterpret_cast<bf16x8*>(&kfa[2 * ct]), qf0, sc[ct], 0, 0, 0);
      sc[ct] = __builtin_amdgcn_mfma_f32_16x16x32_bf16(
          *reinterpret_cast<bf16x8*>(&kfa[2 * ct + 1]), qf1, sc[ct], 0, 0, 0);
    }
    #pragma unroll
    for (int ct = 5; ct < 10; ct++) {
      sc[ct] = __builtin_amdgcn_mfma_f32_16x16x32_bf16(
          *reinterpret_cast<bf16x8*>(&kfb[2 * (ct - 5)]), qf0, sc[ct], 0, 0, 0);
      sc[ct] = __builtin_amdgcn_mfma_f32_16x16x32_bf16(
          *reinterpret_cast<bf16x8*>(&kfb[2 * (ct - 5) + 1]), qf1, sc[ct], 0, 0, 0);
    }

    // softmax over ki
    float mx = -3e38f;
    #pragma unroll
    for (int ct = 0; ct < 10; ct++)
      #pragma unroll
      for (int r = 0; r < 4; r++) mx = fmaxf(mx, sc[ct][r]);
    mx = fmaxf(mx, __shfl_xor(mx, 16, 64));
    mx = fmaxf(mx, __shfl_xor(mx, 32, 64));
    float sum = 0.f;
    #pragma unroll
    for (int ct = 0; ct < 10; ct++)
      #pragma unroll
      for (int r = 0; r < 4; r++) {
        float p = __expf(sc[ct][r] - mx);
        sc[ct][r] = p;
        sum += p;
      }
    sum += __shfl_xor(sum, 16, 64);
    sum += __shfl_xor(sum, 32, 64);
    float inv = 1.f / sum;

    // P (bf16) to per-wave LDS (C-layout -> A-layout transpose)
    #pragma unroll
    for (int ct = 0; ct < 10; ct++) {
      ushort4 pk;
      pk.x = f2bf(sc[ct][0] * inv);
      pk.y = f2bf(sc[ct][1] * inv);
      pk.z = f2bf(sc[ct][2] * inv);
      pk.w = f2bf(sc[ct][3] * inv);
      *reinterpret_cast<ushort4*>(&plds[w][l15][ct * 16 + l4 * 4]) = pk;
    }

    // PV from resident V registers
    #pragma unroll
    for (int ntl = 0; ntl < 2; ntl++) {
      f32x4 pacc;
      #pragma unroll
      for (int e = 0; e < 4; e++) pacc[e] = 0.f;
      #pragma unroll
      for (int ks = 0; ks < 5; ks++) {
        bf16x8 pa = *reinterpret_cast<const bf16x8*>(
            &plds[w][l15][ks * 32 + l4 * 8]);
        pacc = __builtin_amdgcn_mfma_f32_16x16x32_bf16(
            pa, *reinterpret_cast<bf16x8*>(&vba[ntl * 5 + ks]), pacc, 0, 0, 0);
      }
      #pragma unroll
      for (int r = 0; r < 4; r++) {
        int s = r0 + l4 * 4 + r;
        if (s < SEQ)
          out[((size_t)b * SEQ + s) * DMODEL + h * HD + ntl * 16 + l15] = pacc[r];
      }
    }
    #pragma unroll
    for (int ntl = 2; ntl < 4; ntl++) {
      f32x4 pacc;
      #pragma unroll
      for (int e = 0; e < 4; e++) pacc[e] = 0.f;
      #pragma unroll
      for (int ks = 0; ks < 5; ks++) {
        bf16x8 pa = *reinterpret_cast<const bf16x8*>(
            &plds[w][l15][ks * 32 + l4 * 8]);
        pacc = __builtin_amdgcn_mfma_f32_16x16x32_bf16(
            pa, *reinterpret_cast<bf16x8*>(&vbb[(ntl - 2) * 5 + ks]), pacc, 0, 0, 0);
      }
      #pragma unroll
      for (int r = 0; r < 4; r++) {
        int s = r0 + l4 * 4 + r;
        if (s < SEQ)
          out[((size_t)b * SEQ + s) * DMODEL + h * HD + ntl * 16 + l15] = pacc[r];
      }
    }
  }
}

extern "C" void kernel_launch(void* const* d_in, const int* in_sizes, int n_in,
                              void* d_out, int out_size, void* d_ws, size_t ws_size,
                              hipStream_t stream) {
  const float* x    = (const float*)d_in[0];
  const float* mask = (const float*)d_in[1];
  const float* Wq   = (const float*)d_in[2];
  const float* bq   = (const float*)d_in[3];
  const float* Wk   = (const float*)d_in[4];
  const float* Wv   = (const float*)d_in[5];
  const float* bv   = (const float*)d_in[6];
  const float* tbl  = (const float*)d_in[7];
  float* out = (float*)d_out;

  char* ws = (char*)d_ws;
  ushort* Wt = (ushort*)ws;                         // 3,538,944 B
  size_t off = (size_t)NTOT * DMODEL * 2;
  ushort* qbuf = (ushort*)(ws + off); off += (size_t)BDIM * NH * SEQ * HD * 2;
  ushort* kbuf = (ushort*)(ws + off); off += (size_t)BDIM * NH * SEQ * HD * 2;
  ushort* vbuf = (ushort*)(ws + off); off += (size_t)BDIM * NH * HD * SP * 2;
  float*  rbias = (float*)(ws + off); off += (size_t)NH * SEQ * RBS * 4 + 64;
  // ~713 MB of d_ws

  // bf16 x lives in d_out scratch (456 MB f32 out >= 228 MB bf16 x);
  // attn_kernel later overwrites every element of d_out.
  ushort* xbuf = (ushort*)d_out;

  prep_all<<<NP1 + NP2 + NP3, 256, 0, stream>>>(Wq, Wk, Wv, Wt, vbuf, tbl, rbias);
  {
    size_t total = (size_t)BDIM * SEQ * DMODEL;
    x2bf<<<(int)(total / 8 / 256), 256, 0, stream>>>(x, xbuf);
  }

  qkv_gemm<<<GNWG, 512, 0, stream>>>(xbuf, Wt, bq, bv, qbuf, kbuf, vbuf);

  attn_kernel<<<BDIM * 3, 256, 0, stream>>>(qbuf, kbuf, vbuf, mask, rbias, out);
}